// Round 18
// baseline (430.677 us; speedup 1.0000x reference)
//
#include <hip/hip_runtime.h>

#define NODES  50000
#define EDGES  800000
#define GRAPHS 1024
#define P      200      // pitch (floats) for 198-wide node buffers

#define SCAN_BLK 256
#define SCAN_NB  ((NODES + SCAN_BLK - 1) / SCAN_BLK)   // 196

typedef __attribute__((ext_vector_type(8))) short short8v;  // 8 bf16 (4 VGPRs)
typedef __attribute__((ext_vector_type(4))) short short4v;  // 4 bf16 (2 VGPRs)
typedef __attribute__((ext_vector_type(4))) float f32x4;    // MFMA accumulator

__device__ __forceinline__ ushort f2bf(float f) {           // fp32 -> bf16 RNE
    uint u = __float_as_uint(f);
    u = u + 0x7FFFu + ((u >> 16) & 1u);
    return (ushort)(u >> 16);
}

// ---------------------------------------------------------------------------
// CSR build (+ per-graph node counts folded into hist)
// ---------------------------------------------------------------------------
__global__ void hist_kernel(const int* __restrict__ dst, int* __restrict__ deg,
                            const int* __restrict__ batch, int* __restrict__ cnt) {
    int e = blockIdx.x * blockDim.x + threadIdx.x;
    if (e < EDGES) atomicAdd(&deg[dst[e]], 1);
    if (e < NODES) atomicAdd(&cnt[batch[e]], 1);
}

__global__ void scan_part(const int* __restrict__ deg, int* __restrict__ part) {
    __shared__ int sh[SCAN_BLK];
    int t = threadIdx.x;
    int n = blockIdx.x * SCAN_BLK + t;
    sh[t] = (n < NODES) ? deg[n] : 0;
    __syncthreads();
    for (int off = SCAN_BLK / 2; off > 0; off >>= 1) {
        if (t < off) sh[t] += sh[t + off];
        __syncthreads();
    }
    if (t == 0) part[blockIdx.x] = sh[0];
}

__global__ void scan_scan(int* __restrict__ part) {
    __shared__ int sh[SCAN_BLK];
    int t = threadIdx.x;
    int v = (t < SCAN_NB) ? part[t] : 0;
    sh[t] = v;
    __syncthreads();
    for (int off = 1; off < SCAN_BLK; off <<= 1) {
        int u = 0;
        if (t >= off) u = sh[t - off];
        __syncthreads();
        if (t >= off) sh[t] += u;
        __syncthreads();
    }
    if (t < SCAN_NB) part[t] = sh[t] - v;   // exclusive
}

__global__ void scan_expand(const int* __restrict__ deg, const int* __restrict__ part,
                            int* __restrict__ rowstart, int* __restrict__ cursor) {
    __shared__ int sh[SCAN_BLK];
    int t = threadIdx.x;
    int n = blockIdx.x * SCAN_BLK + t;
    int v = (n < NODES) ? deg[n] : 0;
    sh[t] = v;
    __syncthreads();
    for (int off = 1; off < SCAN_BLK; off <<= 1) {
        int u = 0;
        if (t >= off) u = sh[t - off];
        __syncthreads();
        if (t >= off) sh[t] += u;
        __syncthreads();
    }
    int excl = sh[t] - v + part[blockIdx.x];
    if (n < NODES) {
        rowstart[n] = excl;
        cursor[n]   = excl;
        if (n == NODES - 1) rowstart[NODES] = excl + v;
    }
}

__global__ void scatter_kernel(const int* __restrict__ src, const int* __restrict__ dst,
                               int* __restrict__ cursor, int* __restrict__ csrc) {
    int e = blockIdx.x * blockDim.x + threadIdx.x;
    if (e < EDGES) {
        int p = atomicAdd(&cursor[dst[e]], 1);
        csrc[p] = src[e];
    }
}

// ---------------------------------------------------------------------------
// ALL weights -> MFMA-fragment-ordered bf16 hi/lo, one dispatch.
// WF3 padded to 8 fragment chunks, WF6 to 2 (even counts for KT=64 compute).
// ---------------------------------------------------------------------------
__global__ void pad_all(const float* __restrict__ w1a, const float* __restrict__ w1b,
                        const float* __restrict__ w2a, const float* __restrict__ w2b,
                        const float* __restrict__ w3a, const float* __restrict__ w3b,
                        ushort* __restrict__ WF1, ushort* __restrict__ WF2,
                        ushort* __restrict__ WF3, ushort* __restrict__ WF4,
                        ushort* __restrict__ WF5, ushort* __restrict__ WF6) {
    int s = blockIdx.x * blockDim.x + threadIdx.x;
    const float* W; ushort* out; int K, N, NCH, CT, base;
    if      (s < 65536)  { W = w1a; out = WF1; K = 114; N = 198; NCH = 4; CT = 16; base = 0; }
    else if (s < 180224) { W = w1b; out = WF2; K = 198; N = 198; NCH = 7; CT = 16; base = 65536; }
    else if (s < 212992) { W = w2a; out = WF3; K = 198; N = 64;  NCH = 8; CT = 4;  base = 180224; }
    else if (s < 221184) { W = w2b; out = WF4; K = 64;  N = 64;  NCH = 2; CT = 4;  base = 212992; }
    else if (s < 229376) { W = w3a; out = WF5; K = 64;  N = 32;  NCH = 2; CT = 4;  base = 221184; }
    else if (s < 237568) { W = w3b; out = WF6; K = 32;  N = 32;  NCH = 2; CT = 4;  base = 229376; }
    else return;
    int idx = s - base;
    int half = NCH * CT * 512;
    int h = idx / half, r = idx % half;
    int j = r & 7, col = (r >> 3) & 15, kg = (r >> 7) & 3;
    int rest = r >> 9;
    int ct = rest % CT, c = rest / CT;
    int k = c * 32 + kg * 8 + j;
    int n = ct * 16 + col;
    float v = (k < K && n < N) ? W[k * N + n] : 0.0f;
    ushort hi = f2bf(v);
    if (h == 0) out[idx] = hi;
    else {
        float hf = __uint_as_float(((uint)hi) << 16);
        out[idx] = f2bf(v - hf);
    }
}

// ---------------------------------------------------------------------------
// Aggregation: ILP-unrolled gathers.
// D==114: float2 (lanes 0..56). D==32: TWO nodes per wave (half-lanes each).
// ---------------------------------------------------------------------------
template<int D>
__global__ void csr_agg(const float* __restrict__ feat, int fpitch,
                        const int* __restrict__ rowstart, const int* __restrict__ csrc,
                        float* __restrict__ agg, int opitch) {
    int wid  = (blockIdx.x * blockDim.x + threadIdx.x) >> 6;
    int lane = threadIdx.x & 63;
    constexpr int UNR = 8;
    if constexpr (D == 32) {
        const int half = lane >> 5, sub = lane & 31;
        const int node = 2 * wid + half;
        const bool nact = node < NODES;
        const int r0 = nact ? rowstart[node] : 0;
        const int r1 = nact ? rowstart[node + 1] : 0;
        float s = 0.0f;
        for (int base = r0; base < r1; base += 32) {
            const int myidx = (base + sub < r1) ? csrc[base + sub] : 0;
            const int cnt = min(32, r1 - base);
            int t = 0;
            for (; t + UNR <= cnt; t += UNR) {
                const float* p[UNR];
#pragma unroll
                for (int u = 0; u < UNR; u++)
                    p[u] = feat + (size_t)__shfl(myidx, 32 * half + t + u) * fpitch;
                float v[UNR];
#pragma unroll
                for (int u = 0; u < UNR; u++) v[u] = p[u][sub];
                float acc = 0.0f;
#pragma unroll
                for (int u = 0; u < UNR; u++) acc += v[u];
                s += acc;
            }
            for (; t < cnt; t++) {
                const float* fp2 = feat + (size_t)__shfl(myidx, 32 * half + t) * fpitch;
                s += fp2[sub];
            }
        }
        if (nact) agg[(size_t)node * opitch + sub] = s;
    } else if constexpr (D == 114) {
        if (wid >= NODES) return;
        const int r0 = rowstart[wid], r1 = rowstart[wid + 1];
        const bool act = lane < 57;
        float sx = 0.0f, sy = 0.0f;
        for (int base = r0; base < r1; base += 64) {
            const int myidx = (base + lane < r1) ? csrc[base + lane] : 0;
            const int cnt = min(64, r1 - base);
            int t = 0;
            for (; t + UNR <= cnt; t += UNR) {
                const float2* p[UNR];
#pragma unroll
                for (int u = 0; u < UNR; u++)
                    p[u] = (const float2*)(feat + (size_t)__shfl(myidx, t + u) * fpitch);
                float2 v[UNR];
#pragma unroll
                for (int u = 0; u < UNR; u++) if (act) v[u] = p[u][lane];
                if (act) {
                    float ax = 0.0f, ay = 0.0f;
#pragma unroll
                    for (int u = 0; u < UNR; u++) { ax += v[u].x; ay += v[u].y; }
                    sx += ax; sy += ay;
                }
            }
            for (; t < cnt; t++) {
                const float2* fp2 = (const float2*)(feat + (size_t)__shfl(myidx, t) * fpitch);
                if (act) { float2 v = fp2[lane]; sx += v.x; sy += v.y; }
            }
        }
        if (act) *(float2*)(agg + (size_t)wid * opitch + 2 * lane) = make_float2(sx, sy);
    } else {
        if (wid >= NODES) return;
        const int r0 = rowstart[wid], r1 = rowstart[wid + 1];
        float s = 0.0f;
        for (int base = r0; base < r1; base += 64) {
            const int myidx = (base + lane < r1) ? csrc[base + lane] : 0;
            const int cnt = min(64, r1 - base);
            int t = 0;
            for (; t + UNR <= cnt; t += UNR) {
                const float* p[UNR];
#pragma unroll
                for (int u = 0; u < UNR; u++)
                    p[u] = feat + (size_t)__shfl(myidx, t + u) * fpitch;
                float v[UNR];
#pragma unroll
                for (int u = 0; u < UNR; u++)
                    if (lane < D) v[u] = p[u][lane];
                if (lane < D) {
                    float acc = 0.0f;
#pragma unroll
                    for (int u = 0; u < UNR; u++) acc += v[u];
                    s += acc;
                }
            }
            for (; t < cnt; t++) {
                const float* fp2 = feat + (size_t)__shfl(myidx, t) * fpitch;
                if (lane < D) s += fp2[lane];
            }
        }
        if (lane < D) agg[(size_t)wid * opitch + lane] = s;
    }
}

// ---------------------------------------------------------------------------
// FUSED layer-1 kernel: h1 = relu( relu((x + agg)@W1a + b1a) @ W1b + b1b )
// Phase 1 now depth-2 register prefetch; rest unchanged from r17.
// ---------------------------------------------------------------------------
__launch_bounds__(256)
__global__ void gemm_fused_l1(const float* __restrict__ X,
                              const float* __restrict__ A2,
                              const ushort* __restrict__ WF1,
                              const float* __restrict__ B1,
                              const ushort* __restrict__ WF2,
                              const float* __restrict__ B2,
                              float* __restrict__ OUT,
                              float* __restrict__ gsum, float* __restrict__ gsq) {
    constexpr int K1   = 114;
    constexpr int NCH1 = 4;
    constexpr int NCH2 = 7;
    constexpr int CT   = 16;
    constexpr int CTW  = 4;
    constexpr int NN   = 198;

    __shared__ __align__(16) ushort A_lds[2][2][2][4][16][8];
    __shared__ __align__(16) ushort M_lds[2][NCH2][2][4][16][8];
    __shared__ float shSum[256];
    __shared__ float shSq [256];

    const int tid  = threadIdx.x;
    const int lane = tid & 63;
    const int wv   = tid >> 6;
    const int node0 = blockIdx.x * 32;

    for (int n = tid; n < 256; n += 256) { shSum[n] = 0.0f; shSq[n] = 0.0f; }

    const int sr  = tid >> 3;
    const int sc4 = (tid & 7) * 4;
    const int skg = sc4 >> 3;
    const int sj0 = sc4 & 7;
    const int gn  = node0 + sr;
    const size_t fstride1 = (size_t)NCH1 * CT * 512;
    const size_t fstride2 = (size_t)NCH2 * CT * 512;

    float xvA[4], a2vA[4], xvB[4], a2vB[4];

    auto loadA_A = [&](int c) {
        const int k0 = c * 32 + sc4;
#pragma unroll
        for (int j = 0; j < 4; j++) {
            int gk = k0 + j;
            bool ok = (gn < NODES && gk < K1);
            xvA[j]  = ok ? X[(size_t)gn * K1 + gk] : 0.0f;
            a2vA[j] = ok ? A2[(size_t)gn * P + gk] : 0.0f;
        }
    };
    auto loadA_B = [&](int c) {
        const int k0 = c * 32 + sc4;
#pragma unroll
        for (int j = 0; j < 4; j++) {
            int gk = k0 + j;
            bool ok = (gn < NODES && gk < K1);
            xvB[j]  = ok ? X[(size_t)gn * K1 + gk] : 0.0f;
            a2vB[j] = ok ? A2[(size_t)gn * P + gk] : 0.0f;
        }
    };
    auto cvtStore = [&](int buf, int c, const float* xv, const float* a2v) {
        const int k0 = c * 32 + sc4;
        short4v hv, lv;
#pragma unroll
        for (int j = 0; j < 4; j++) {
            int gk = k0 + j;
            float t = 0.0f;
            if (gn < NODES && gk < K1) t = xv[j] + a2v[j];
            ushort h = f2bf(t);
            float hf = __uint_as_float(((uint)h) << 16);
            ushort l = f2bf(t - hf);
            hv[j] = (short)h; lv[j] = (short)l;
        }
        *(short4v*)&A_lds[buf][0][sr >> 4][skg][sr & 15][sj0] = hv;
        *(short4v*)&A_lds[buf][1][sr >> 4][skg][sr & 15][sj0] = lv;
    };

    f32x4 acc1[2][CTW] = {};
    loadA_A(0);
    loadA_B(1);
    cvtStore(0, 0, xvA, a2vA);
    __syncthreads();

    const int kg = lane >> 4, rw = lane & 15;
#pragma unroll
    for (int c = 0; c < NCH1; c++) {
        const int buf = c & 1;
        if (c + 2 < NCH1) {
            if ((c & 1) == 0) loadA_A(c + 2);
            else              loadA_B(c + 2);
        }

        short8v ah[2], al[2];
#pragma unroll
        for (int rt = 0; rt < 2; rt++) {
            ah[rt] = *(const short8v*)&A_lds[buf][0][rt][kg][rw][0];
            al[rt] = *(const short8v*)&A_lds[buf][1][rt][kg][rw][0];
        }
        const size_t fb0 = ((size_t)(c * CT + wv * CTW)) * 512 + (size_t)lane * 8;
        short8v wh = *(const short8v*)(WF1 + fb0);
        short8v wl = *(const short8v*)(WF1 + fstride1 + fb0);
#pragma unroll
        for (int t = 0; t < CTW; t++) {
            short8v nwh, nwl;
            if (t + 1 < CTW) {
                const size_t fb = fb0 + (size_t)(t + 1) * 512;
                nwh = *(const short8v*)(WF1 + fb);
                nwl = *(const short8v*)(WF1 + fstride1 + fb);
            }
            __builtin_amdgcn_s_setprio(1);
#pragma unroll
            for (int rt = 0; rt < 2; rt++) {
                acc1[rt][t] = __builtin_amdgcn_mfma_f32_16x16x32_bf16(ah[rt], wh, acc1[rt][t], 0, 0, 0);
                acc1[rt][t] = __builtin_amdgcn_mfma_f32_16x16x32_bf16(al[rt], wh, acc1[rt][t], 0, 0, 0);
                acc1[rt][t] = __builtin_amdgcn_mfma_f32_16x16x32_bf16(ah[rt], wl, acc1[rt][t], 0, 0, 0);
            }
            __builtin_amdgcn_s_setprio(0);
            if (t + 1 < CTW) { wh = nwh; wl = nwl; }
        }
        if (c + 1 < NCH1) {
            if (((c + 1) & 1) == 0) cvtStore((c + 1) & 1, c + 1, xvA, a2vA);
            else                    cvtStore((c + 1) & 1, c + 1, xvB, a2vB);
        }
        __syncthreads();
    }

    const int mg = lane >> 4, colb = lane & 15;
#pragma unroll
    for (int t = 0; t < CTW; t++) {
        const int ct = wv * CTW + t;
        if (ct >= 14) continue;
        const int n = ct * 16 + colb;
        const float bn = (n < NN) ? B1[n] : 0.0f;
        const int c2 = n >> 5, kg2 = (n >> 3) & 3, j2 = n & 7;
#pragma unroll
        for (int rt = 0; rt < 2; rt++) {
#pragma unroll
            for (int j = 0; j < 4; j++) {
                float vv = fmaxf(acc1[rt][t][j] + bn, 0.0f);
                if (n >= NN) vv = 0.0f;
                ushort h = f2bf(vv);
                float hf = __uint_as_float(((uint)h) << 16);
                ushort l = f2bf(vv - hf);
                int row = mg * 4 + j;
                M_lds[0][c2][rt][kg2][row][j2] = h;
                M_lds[1][c2][rt][kg2][row][j2] = l;
            }
        }
    }
    __syncthreads();

    f32x4 acc2[2][CTW] = {};
#pragma unroll
    for (int c = 0; c < NCH2; c++) {
        short8v ah[2], al[2];
#pragma unroll
        for (int rt = 0; rt < 2; rt++) {
            ah[rt] = *(const short8v*)&M_lds[0][c][rt][kg][rw][0];
            al[rt] = *(const short8v*)&M_lds[1][c][rt][kg][rw][0];
        }
        const size_t fb0 = ((size_t)(c * CT + wv * CTW)) * 512 + (size_t)lane * 8;
        short8v wh = *(const short8v*)(WF2 + fb0);
        short8v wl = *(const short8v*)(WF2 + fstride2 + fb0);
#pragma unroll
        for (int t = 0; t < CTW; t++) {
            short8v nwh, nwl;
            if (t + 1 < CTW) {
                const size_t fb = fb0 + (size_t)(t + 1) * 512;
                nwh = *(const short8v*)(WF2 + fb);
                nwl = *(const short8v*)(WF2 + fstride2 + fb);
            }
            __builtin_amdgcn_s_setprio(1);
#pragma unroll
            for (int rt = 0; rt < 2; rt++) {
                acc2[rt][t] = __builtin_amdgcn_mfma_f32_16x16x32_bf16(ah[rt], wh, acc2[rt][t], 0, 0, 0);
                acc2[rt][t] = __builtin_amdgcn_mfma_f32_16x16x32_bf16(al[rt], wh, acc2[rt][t], 0, 0, 0);
                acc2[rt][t] = __builtin_amdgcn_mfma_f32_16x16x32_bf16(ah[rt], wl, acc2[rt][t], 0, 0, 0);
            }
            __builtin_amdgcn_s_setprio(0);
            if (t + 1 < CTW) { wh = nwh; wl = nwl; }
        }
    }

#pragma unroll
    for (int t = 0; t < CTW; t++) {
        const int ct = wv * CTW + t;
        const int n = ct * 16 + colb;
        const float bn = (n < NN) ? B2[n] : 0.0f;
        float psum = 0.0f, psq = 0.0f;
#pragma unroll
        for (int rt = 0; rt < 2; rt++) {
#pragma unroll
            for (int j = 0; j < 4; j++) {
                int m = node0 + rt * 16 + mg * 4 + j;
                float vv = fmaxf(acc2[rt][t][j] + bn, 0.0f);
                if (m < NODES && n < NN) {
                    OUT[(size_t)m * P + n] = vv;
                    psum += vv; psq += vv * vv;
                }
            }
        }
        if (n < NN) {
            atomicAdd(&shSum[n], psum);
            atomicAdd(&shSq[n], psq);
        }
    }
    __syncthreads();
    for (int n = tid; n < NN; n += 256) {
        atomicAdd(&gsum[n], shSum[n]);
        atomicAdd(&gsq[n], shSq[n]);
    }
}

// ---------------------------------------------------------------------------
// MFMA GEMM (layers 2/3), bf16 hi/lo, KT=64 compute chunks (half the serial
// barrier-phased steps), depth-2 register prefetch.
// A_lds: [buf][h][rt][sub][kg][row][j]; sub selects the 32-k half.
// BNX: BN coeffs derived in-kernel into LDS. WRITE/POOL as before.
// WF must be zero-padded to 2*CC fragment chunks (pad_all ensures).
// ---------------------------------------------------------------------------
template<int K, int N, bool ADD2, bool STATS, bool BNX, bool PRE, bool ACT,
         bool WRITE, bool POOL>
__launch_bounds__(256)
__global__ void gemm_mfma(const float* __restrict__ X, int xpitch,
                          const float* __restrict__ A2, int apitch,
                          const ushort* __restrict__ WF,
                          const float* __restrict__ B,
                          const float* __restrict__ PREB,
                          const float* __restrict__ bnsum, const float* __restrict__ bnsq,
                          const float* __restrict__ gamma, const float* __restrict__ beta,
                          float* __restrict__ OUT, int opitch,
                          float* __restrict__ gsum, float* __restrict__ gsq,
                          const int* __restrict__ batch, float* __restrict__ gpool) {
    constexpr int NCH32 = (K + 31) / 32;        // fragment chunks with data
    constexpr int CC    = (NCH32 + 1) / 2;      // 64-wide compute chunks
    constexpr int NF    = 2 * CC;               // fragment chunks in WF (padded)
    constexpr int NBUF  = (CC > 1) ? 2 : 1;
    constexpr int NP  = ((N + 63) / 64) * 64;
    constexpr int CT  = NP / 16;
    constexpr int CTW = CT / 4;
    static_assert(CT % 4 == 0, "col tiles must split across 4 waves");

    __shared__ __align__(16) ushort A_lds[NBUF][2][2][2][4][16][8];
    __shared__ float shSum[STATS ? NP : 4];
    __shared__ float shSq [STATS ? NP : 4];
    __shared__ float shSc [BNX ? 256 : 4];
    __shared__ float shSh [BNX ? 256 : 4];

    const int tid  = threadIdx.x;
    const int lane = tid & 63;
    const int wv   = tid >> 6;
    const int node0 = blockIdx.x * 32;

    if (STATS) {
        for (int n = tid; n < NP; n += 256) { shSum[n] = 0.0f; shSq[n] = 0.0f; }
    }
    if (BNX) {
        if (tid < K) {
            float mean = bnsum[tid] * (1.0f / NODES);
            float var  = bnsq[tid] * (1.0f / NODES) - mean * mean;
            var = var < 0.0f ? 0.0f : var;
            float sc = gamma[tid] * rsqrtf(var + 1e-5f);
            shSc[tid] = sc;
            shSh[tid] = beta[tid] - mean * sc;
        }
        __syncthreads();
    }

    f32x4 acc[2][CTW] = {};

    const int sr  = tid >> 3;            // staging row 0..31
    const int so  = tid & 7;             // k-octet: sub = so>>2, kg = so&3
    const int gn  = node0 + sr;
    const size_t fstride = (size_t)NF * CT * 512;

    float xvA[8], xvB[8];
    float a2vA[ADD2 ? 8 : 1], a2vB[ADD2 ? 8 : 1];

    auto loadA_A = [&](int c) {
        const int k0 = c * 64 + so * 8;
#pragma unroll
        for (int j = 0; j < 8; j++) {
            int gk = k0 + j;
            bool ok = (gn < NODES && gk < K);
            xvA[j] = ok ? X[(size_t)gn * xpitch + gk] : 0.0f;
            if (ADD2) a2vA[j] = ok ? A2[(size_t)gn * apitch + gk] : 0.0f;
        }
    };
    auto loadA_B = [&](int c) {
        const int k0 = c * 64 + so * 8;
#pragma unroll
        for (int j = 0; j < 8; j++) {
            int gk = k0 + j;
            bool ok = (gn < NODES && gk < K);
            xvB[j] = ok ? X[(size_t)gn * xpitch + gk] : 0.0f;
            if (ADD2) a2vB[j] = ok ? A2[(size_t)gn * apitch + gk] : 0.0f;
        }
    };
    auto cvtCore = [&](int buf, int c, const float* xv, const float* a2v) {
        const int k0 = c * 64 + so * 8;
        short8v hv, lv;
#pragma unroll
        for (int j = 0; j < 8; j++) {
            int gk = k0 + j;
            float t = 0.0f;
            if (gn < NODES && gk < K) {
                t = xv[j];
                if (BNX) t = fmaf(t, shSc[gk], shSh[gk]);
                if (ADD2) t += a2v[j];
                if (PRE)  t = fmaxf(t + PREB[gk], 0.0f);
            }
            ushort h = f2bf(t);
            float hf = __uint_as_float(((uint)h) << 16);
            ushort l = f2bf(t - hf);
            hv[j] = (short)h; lv[j] = (short)l;
        }
        *(short8v*)&A_lds[buf][0][sr >> 4][so >> 2][so & 3][sr & 15][0] = hv;
        *(short8v*)&A_lds[buf][1][sr >> 4][so >> 2][so & 3][sr & 15][0] = lv;
    };

    loadA_A(0);
    if (CC > 1) loadA_B(1);
    cvtCore(0, 0, xvA, ADD2 ? a2vA : xvA);
    __syncthreads();

    const int kg = lane >> 4, rw = lane & 15;
#pragma unroll
    for (int c = 0; c < CC; c++) {
        const int buf = (NBUF == 2) ? (c & 1) : 0;
        if (c + 2 < CC) {
            if ((c & 1) == 0) loadA_A(c + 2);
            else              loadA_B(c + 2);
        }

#pragma unroll
        for (int sub = 0; sub < 2; sub++) {
            short8v ah[2], al[2];
#pragma unroll
            for (int rt = 0; rt < 2; rt++) {
                ah[rt] = *(const short8v*)&A_lds[buf][0][rt][sub][kg][rw][0];
                al[rt] = *(const short8v*)&A_lds[buf][1][rt][sub][kg][rw][0];
            }
            const int fc = 2 * c + sub;
            const size_t fb0 = ((size_t)(fc * CT + wv * CTW)) * 512 + (size_t)lane * 8;
            short8v wh = *(const short8v*)(WF + fb0);
            short8v wl = *(const short8v*)(WF + fstride + fb0);
#pragma unroll
            for (int t = 0; t < CTW; t++) {
                short8v nwh, nwl;
                if (t + 1 < CTW) {
                    const size_t fb = fb0 + (size_t)(t + 1) * 512;
                    nwh = *(const short8v*)(WF + fb);
                    nwl = *(const short8v*)(WF + fstride + fb);
                }
                __builtin_amdgcn_s_setprio(1);
#pragma unroll
                for (int rt = 0; rt < 2; rt++) {
                    acc[rt][t] = __builtin_amdgcn_mfma_f32_16x16x32_bf16(ah[rt], wh, acc[rt][t], 0, 0, 0);
                    acc[rt][t] = __builtin_amdgcn_mfma_f32_16x16x32_bf16(al[rt], wh, acc[rt][t], 0, 0, 0);
                    acc[rt][t] = __builtin_amdgcn_mfma_f32_16x16x32_bf16(ah[rt], wl, acc[rt][t], 0, 0, 0);
                }
                __builtin_amdgcn_s_setprio(0);
                if (t + 1 < CTW) { wh = nwh; wl = nwl; }
            }
        }

        if (c + 1 < CC) {
            if (((c + 1) & 1) == 0) cvtCore((c + 1) & 1, c + 1, xvA, ADD2 ? a2vA : xvA);
            else                    cvtCore((c + 1) & 1, c + 1, xvB, ADD2 ? a2vB : xvB);
        }
        __syncthreads();
    }

    const int mg = lane >> 4, colb = lane & 15;
#pragma unroll
    for (int t = 0; t < CTW; t++) {
        const int ct = wv * CTW + t;
        const int n = ct * 16 + colb;
        const float bn = (ACT && n < N) ? B[n] : 0.0f;
        float psum = 0.0f, psq = 0.0f;
#pragma unroll
        for (int rt = 0; rt < 2; rt++) {
#pragma unroll
            for (int j = 0; j < 4; j++) {
                int m = node0 + rt * 16 + mg * 4 + j;
                float vv = ACT ? fmaxf(acc[rt][t][j] + bn, 0.0f) : acc[rt][t][j];
                if (m < NODES && n < N) {
                    if (WRITE) OUT[(size_t)m * opitch + n] = vv;
                    if (STATS) { psum += vv; psq += vv * vv; }
                    if (POOL)  atomicAdd(&gpool[batch[m] * 32 + n], vv);
                }
            }
        }
        if (STATS && n < N) {
            atomicAdd(&shSum[n], psum);
            atomicAdd(&shSq[n], psq);
        }
    }
    if (STATS) {
        __syncthreads();
        for (int n = tid; n < N; n += 256) {
            atomicAdd(&gsum[n], shSum[n]);
            atomicAdd(&gsq[n], shSq[n]);
        }
    }
}

// ---------------------------------------------------------------------------
// Head MLP; BN3 coefficients derived inline, applied via linearity.
// ---------------------------------------------------------------------------
__global__ void head_kernel(const float* __restrict__ graw, const int* __restrict__ cnt,
                            const float* __restrict__ bnsum, const float* __restrict__ bnsq,
                            const float* __restrict__ gamma, const float* __restrict__ beta,
                            const float* __restrict__ fw1, const float* __restrict__ fb1,
                            const float* __restrict__ fw2, const float* __restrict__ fb2,
                            const float* __restrict__ ow, const float* __restrict__ ob,
                            float* __restrict__ out) {
    int gi = blockIdx.x * blockDim.x + threadIdx.x;
    if (gi >= GRAPHS) return;
    float cf = (float)cnt[gi];
    float v[32];
#pragma unroll
    for (int k = 0; k < 32; k++) {
        float mean = bnsum[k] * (1.0f / NODES);
        float var  = bnsq[k] * (1.0f / NODES) - mean * mean;
        var = var < 0.0f ? 0.0f : var;
        float sc = gamma[k] * rsqrtf(var + 1e-5f);
        float sh = beta[k] - mean * sc;
        v[k] = fmaf(graw[gi * 32 + k], sc, cf * sh);
    }
    float a1[16];
#pragma unroll
    for (int o = 0; o < 16; o++) {
        float s = fb1[o];
#pragma unroll
        for (int k = 0; k < 32; k++) s = fmaf(v[k], fw1[k * 16 + o], s);
        a1[o] = s > 0.0f ? s : 0.0f;
    }
    float a2[8];
#pragma unroll
    for (int o = 0; o < 8; o++) {
        float s = fb2[o];
#pragma unroll
        for (int k = 0; k < 16; k++) s = fmaf(a1[k], fw2[k * 8 + o], s);
        a2[o] = s > 0.0f ? s : 0.0f;
    }
#pragma unroll
    for (int o = 0; o < 2; o++) {
        float s = ob[o];
#pragma unroll
        for (int k = 0; k < 8; k++) s = fmaf(a2[k], ow[k * 2 + o], s);
        out[gi * 2 + o] = s;
    }
}

// ---------------------------------------------------------------------------
extern "C" void kernel_launch(void* const* d_in, const int* in_sizes, int n_in,
                              void* d_out, int out_size, void* d_ws, size_t ws_size,
                              hipStream_t stream) {
    const float* x     = (const float*)d_in[0];
    const int*   ei    = (const int*)d_in[1];
    const int*   batch = (const int*)d_in[2];
    const float *w1a = (const float*)d_in[3],  *b1a = (const float*)d_in[4];
    const float *w1b = (const float*)d_in[5],  *b1b = (const float*)d_in[6];
    const float *g1  = (const float*)d_in[7],  *be1 = (const float*)d_in[8];
    const float *w2a = (const float*)d_in[9],  *b2a = (const float*)d_in[10];
    const float *w2b = (const float*)d_in[11], *b2b = (const float*)d_in[12];
    const float *g2  = (const float*)d_in[13], *be2 = (const float*)d_in[14];
    const float *w3a = (const float*)d_in[15], *b3a = (const float*)d_in[16];
    const float *w3b = (const float*)d_in[17], *b3b = (const float*)d_in[18];
    const float *g3  = (const float*)d_in[19], *be3 = (const float*)d_in[20];
    const float *fw1 = (const float*)d_in[21], *fb1 = (const float*)d_in[22];
    const float *fw2 = (const float*)d_in[23], *fb2 = (const float*)d_in[24];
    const float *ow  = (const float*)d_in[25], *ob  = (const float*)d_in[26];
    const int* src = ei;
    const int* dst = ei + EDGES;

    float* ws  = (float*)d_ws;
    float* b0  = ws;                                   // 50000 x 200
    float* b1  = ws + (size_t)NODES * P;               // 50000 x 200
    float* Y2  = b1;                                   // 50000 x 64 (in b1)
    float* AG2 = b1 + (size_t)NODES * 64;              // 50000 x 64 (in b1)
    float* Y3  = b1;                                   // 50000 x 32 (in b1)
    float* AG3 = b1 + (size_t)NODES * 32;              // 50000 x 32 (in b1)

    // ---- contiguous ZERO region (one memset per launch) ----
    int*   deg  = (int*)(ws + (size_t)2 * NODES * P);  // 50000
    int*   cnt  = deg + NODES;                         // 1024
    float* SUM1 = (float*)(cnt + GRAPHS);              // 6 x 256 stat buffers
    float* SQ1  = SUM1 + 256;
    float* SUM2 = SQ1 + 256;
    float* SQ2  = SUM2 + 256;
    float* SUM3 = SQ2 + 256;
    float* SQ3  = SUM3 + 256;
    float* G    = SQ3 + 256;                           // 1024 x 32 raw pool
    const size_t ZERO_ELEMS = (size_t)NODES + GRAPHS + 6 * 256 + (size_t)GRAPHS * 32;
    // ---- end zero region ----

    int* rowstart = (int*)(G + (size_t)GRAPHS * 32);   // 50001
    int* cursor   = rowstart + NODES + 1;              // 50000
    int* part     = cursor + NODES;                    // 256
    int* csrc     = part + 256;                        // 800000
    uintptr_t wfp = ((uintptr_t)(csrc + EDGES) + 15) & ~(uintptr_t)15;
    ushort* WF1 = (ushort*)wfp;                        // 65536
    ushort* WF2 = WF1 + 65536;                         // 114688
    ushort* WF3 = WF2 + 114688;                        // 32768 (8 frag chunks)
    ushort* WF4 = WF3 + 32768;                         // 8192
    ushort* WF5 = WF4 + 8192;                          // 8192
    ushort* WF6 = WF5 + 8192;                          // 8192 (2 frag chunks)
    float* out = (float*)d_out;

    const int GBR  = (NODES + 31) / 32;       // 1563 gemm blocks (32-row)
    const int AB   = (NODES * 64 + 255) / 256;            // 1 node / wave
    const int AB2  = (((NODES + 1) / 2) * 64 + 255) / 256; // 2 nodes / wave
    const int EB   = (EDGES + 255) / 256;

    // ---- weight conversion (1 dispatch) + zeroing (1 memset) ----
    pad_all<<<(237568 + 255) / 256, 256, 0, stream>>>(w1a, w1b, w2a, w2b, w3a, w3b,
                                                      WF1, WF2, WF3, WF4, WF5, WF6);
    hipMemsetAsync(deg, 0, ZERO_ELEMS * sizeof(int), stream);

    // ---- CSR build (+ per-graph counts) ----
    hist_kernel<<<EB, 256, 0, stream>>>(dst, deg, batch, cnt);
    scan_part<<<SCAN_NB, SCAN_BLK, 0, stream>>>(deg, part);
    scan_scan<<<1, SCAN_BLK, 0, stream>>>(part);
    scan_expand<<<SCAN_NB, SCAN_BLK, 0, stream>>>(deg, part, rowstart, cursor);
    scatter_kernel<<<EB, 256, 0, stream>>>(src, dst, cursor, csrc);

    // ---- layer 1 (114 -> 198 -> 198): agg-first + fused double GEMM ----
    csr_agg<114><<<AB, 256, 0, stream>>>(x, 114, rowstart, csrc, b0, P);
    gemm_fused_l1<<<GBR, 256, 0, stream>>>(x, b0, WF1, b1a, WF2, b1b, b0, SUM1, SQ1);

    // ---- layer 2 (198 -> 64 -> 64): aggregate-after at D=64; BN1 in-kernel ----
    gemm_mfma<198, 64, false, false, true, false, false, true, false><<<GBR, 256, 0, stream>>>(
        b0, P, nullptr, 0, WF3, nullptr, nullptr, SUM1, SQ1, g1, be1,
        Y2, 64, nullptr, nullptr, nullptr, nullptr);
    csr_agg<64><<<AB, 256, 0, stream>>>(Y2, 64, rowstart, csrc, AG2, 64);
    gemm_mfma<64, 64, true, true, false, true, true, true, false><<<GBR, 256, 0, stream>>>(
        Y2, 64, AG2, 64, WF4, b2b, b2a, nullptr, nullptr, nullptr, nullptr,
        b0, 64, SUM2, SQ2, nullptr, nullptr);

    // ---- layer 3 (64 -> 32 -> 32): aggregate-after at D=32; BN2 in-kernel ----
    gemm_mfma<64, 32, false, false, true, false, false, true, false><<<GBR, 256, 0, stream>>>(
        b0, 64, nullptr, 0, WF5, nullptr, nullptr, SUM2, SQ2, g2, be2,
        Y3, 32, nullptr, nullptr, nullptr, nullptr);
    csr_agg<32><<<AB2, 256, 0, stream>>>(Y3, 32, rowstart, csrc, AG3, 32);
    gemm_mfma<32, 32, true, true, false, true, true, false, true><<<GBR, 256, 0, stream>>>(
        Y3, 32, AG3, 32, WF6, b3b, b3a, nullptr, nullptr, nullptr, nullptr,
        nullptr, 32, SUM3, SQ3, batch, G);

    // ---- head (BN3 derived inline, applied via linearity) ----
    head_kernel<<<(GRAPHS + 255) / 256, 256, 0, stream>>>(
        G, cnt, SUM3, SQ3, g3, be3, fw1, fb1, fw2, fb2, ow, ob, out);
}

// Round 19
// 404.654 us; speedup vs baseline: 1.0643x; 1.0643x over previous
//
#include <hip/hip_runtime.h>

#define NODES  50000
#define EDGES  800000
#define GRAPHS 1024
#define P      200      // pitch (floats) for 198-wide node buffers

#define SCAN_BLK 256
#define SCAN_NB  ((NODES + SCAN_BLK - 1) / SCAN_BLK)   // 196

typedef __attribute__((ext_vector_type(8))) short short8v;  // 8 bf16 (4 VGPRs)
typedef __attribute__((ext_vector_type(4))) short short4v;  // 4 bf16 (2 VGPRs)
typedef __attribute__((ext_vector_type(4))) float f32x4;    // MFMA accumulator

__device__ __forceinline__ ushort f2bf(float f) {           // fp32 -> bf16 RNE
    uint u = __float_as_uint(f);
    u = u + 0x7FFFu + ((u >> 16) & 1u);
    return (ushort)(u >> 16);
}

// ---------------------------------------------------------------------------
// CSR build (+ per-graph node counts folded into hist)
// ---------------------------------------------------------------------------
__global__ void hist_kernel(const int* __restrict__ dst, int* __restrict__ deg,
                            const int* __restrict__ batch, int* __restrict__ cnt) {
    int e = blockIdx.x * blockDim.x + threadIdx.x;
    if (e < EDGES) atomicAdd(&deg[dst[e]], 1);
    if (e < NODES) atomicAdd(&cnt[batch[e]], 1);
}

__global__ void scan_part(const int* __restrict__ deg, int* __restrict__ part) {
    __shared__ int sh[SCAN_BLK];
    int t = threadIdx.x;
    int n = blockIdx.x * SCAN_BLK + t;
    sh[t] = (n < NODES) ? deg[n] : 0;
    __syncthreads();
    for (int off = SCAN_BLK / 2; off > 0; off >>= 1) {
        if (t < off) sh[t] += sh[t + off];
        __syncthreads();
    }
    if (t == 0) part[blockIdx.x] = sh[0];
}

__global__ void scan_scan(int* __restrict__ part) {
    __shared__ int sh[SCAN_BLK];
    int t = threadIdx.x;
    int v = (t < SCAN_NB) ? part[t] : 0;
    sh[t] = v;
    __syncthreads();
    for (int off = 1; off < SCAN_BLK; off <<= 1) {
        int u = 0;
        if (t >= off) u = sh[t - off];
        __syncthreads();
        if (t >= off) sh[t] += u;
        __syncthreads();
    }
    if (t < SCAN_NB) part[t] = sh[t] - v;   // exclusive
}

__global__ void scan_expand(const int* __restrict__ deg, const int* __restrict__ part,
                            int* __restrict__ rowstart, int* __restrict__ cursor) {
    __shared__ int sh[SCAN_BLK];
    int t = threadIdx.x;
    int n = blockIdx.x * SCAN_BLK + t;
    int v = (n < NODES) ? deg[n] : 0;
    sh[t] = v;
    __syncthreads();
    for (int off = 1; off < SCAN_BLK; off <<= 1) {
        int u = 0;
        if (t >= off) u = sh[t - off];
        __syncthreads();
        if (t >= off) sh[t] += u;
        __syncthreads();
    }
    int excl = sh[t] - v + part[blockIdx.x];
    if (n < NODES) {
        rowstart[n] = excl;
        cursor[n]   = excl;
        if (n == NODES - 1) rowstart[NODES] = excl + v;
    }
}

__global__ void scatter_kernel(const int* __restrict__ src, const int* __restrict__ dst,
                               int* __restrict__ cursor, int* __restrict__ csrc) {
    int e = blockIdx.x * blockDim.x + threadIdx.x;
    if (e < EDGES) {
        int p = atomicAdd(&cursor[dst[e]], 1);
        csrc[p] = src[e];
    }
}

// ---------------------------------------------------------------------------
// ALL weights -> MFMA-fragment-ordered bf16 hi/lo, one dispatch (r17 layout)
// ---------------------------------------------------------------------------
__global__ void pad_all(const float* __restrict__ w1a, const float* __restrict__ w1b,
                        const float* __restrict__ w2a, const float* __restrict__ w2b,
                        const float* __restrict__ w3a, const float* __restrict__ w3b,
                        ushort* __restrict__ WF1, ushort* __restrict__ WF2,
                        ushort* __restrict__ WF3, ushort* __restrict__ WF4,
                        ushort* __restrict__ WF5, ushort* __restrict__ WF6) {
    int s = blockIdx.x * blockDim.x + threadIdx.x;
    const float* W; ushort* out; int K, N, NCH, CT, base;
    if      (s < 65536)  { W = w1a; out = WF1; K = 114; N = 198; NCH = 4; CT = 16; base = 0; }
    else if (s < 180224) { W = w1b; out = WF2; K = 198; N = 198; NCH = 7; CT = 16; base = 65536; }
    else if (s < 208896) { W = w2a; out = WF3; K = 198; N = 64;  NCH = 7; CT = 4;  base = 180224; }
    else if (s < 217088) { W = w2b; out = WF4; K = 64;  N = 64;  NCH = 2; CT = 4;  base = 208896; }
    else if (s < 225280) { W = w3a; out = WF5; K = 64;  N = 32;  NCH = 2; CT = 4;  base = 217088; }
    else if (s < 229376) { W = w3b; out = WF6; K = 32;  N = 32;  NCH = 1; CT = 4;  base = 225280; }
    else return;
    int idx = s - base;
    int half = NCH * CT * 512;
    int h = idx / half, r = idx % half;
    int j = r & 7, col = (r >> 3) & 15, kg = (r >> 7) & 3;
    int rest = r >> 9;
    int ct = rest % CT, c = rest / CT;
    int k = c * 32 + kg * 8 + j;
    int n = ct * 16 + col;
    float v = (k < K && n < N) ? W[k * N + n] : 0.0f;
    ushort hi = f2bf(v);
    if (h == 0) out[idx] = hi;
    else {
        float hf = __uint_as_float(((uint)hi) << 16);
        out[idx] = f2bf(v - hf);
    }
}

// ---------------------------------------------------------------------------
// Aggregation: ILP-unrolled gathers.
// D==114: float2 (lanes 0..56). D==32: TWO nodes per wave (half-lanes each).
// ---------------------------------------------------------------------------
template<int D>
__global__ void csr_agg(const float* __restrict__ feat, int fpitch,
                        const int* __restrict__ rowstart, const int* __restrict__ csrc,
                        float* __restrict__ agg, int opitch) {
    int wid  = (blockIdx.x * blockDim.x + threadIdx.x) >> 6;
    int lane = threadIdx.x & 63;
    constexpr int UNR = 8;
    if constexpr (D == 32) {
        const int half = lane >> 5, sub = lane & 31;
        const int node = 2 * wid + half;
        const bool nact = node < NODES;
        const int r0 = nact ? rowstart[node] : 0;
        const int r1 = nact ? rowstart[node + 1] : 0;
        float s = 0.0f;
        for (int base = r0; base < r1; base += 32) {
            const int myidx = (base + sub < r1) ? csrc[base + sub] : 0;
            const int cnt = min(32, r1 - base);
            int t = 0;
            for (; t + UNR <= cnt; t += UNR) {
                const float* p[UNR];
#pragma unroll
                for (int u = 0; u < UNR; u++)
                    p[u] = feat + (size_t)__shfl(myidx, 32 * half + t + u) * fpitch;
                float v[UNR];
#pragma unroll
                for (int u = 0; u < UNR; u++) v[u] = p[u][sub];
                float acc = 0.0f;
#pragma unroll
                for (int u = 0; u < UNR; u++) acc += v[u];
                s += acc;
            }
            for (; t < cnt; t++) {
                const float* fp2 = feat + (size_t)__shfl(myidx, 32 * half + t) * fpitch;
                s += fp2[sub];
            }
        }
        if (nact) agg[(size_t)node * opitch + sub] = s;
    } else if constexpr (D == 114) {
        if (wid >= NODES) return;
        const int r0 = rowstart[wid], r1 = rowstart[wid + 1];
        const bool act = lane < 57;
        float sx = 0.0f, sy = 0.0f;
        for (int base = r0; base < r1; base += 64) {
            const int myidx = (base + lane < r1) ? csrc[base + lane] : 0;
            const int cnt = min(64, r1 - base);
            int t = 0;
            for (; t + UNR <= cnt; t += UNR) {
                const float2* p[UNR];
#pragma unroll
                for (int u = 0; u < UNR; u++)
                    p[u] = (const float2*)(feat + (size_t)__shfl(myidx, t + u) * fpitch);
                float2 v[UNR];
#pragma unroll
                for (int u = 0; u < UNR; u++) if (act) v[u] = p[u][lane];
                if (act) {
                    float ax = 0.0f, ay = 0.0f;
#pragma unroll
                    for (int u = 0; u < UNR; u++) { ax += v[u].x; ay += v[u].y; }
                    sx += ax; sy += ay;
                }
            }
            for (; t < cnt; t++) {
                const float2* fp2 = (const float2*)(feat + (size_t)__shfl(myidx, t) * fpitch);
                if (act) { float2 v = fp2[lane]; sx += v.x; sy += v.y; }
            }
        }
        if (act) *(float2*)(agg + (size_t)wid * opitch + 2 * lane) = make_float2(sx, sy);
    } else {
        if (wid >= NODES) return;
        const int r0 = rowstart[wid], r1 = rowstart[wid + 1];
        float s = 0.0f;
        for (int base = r0; base < r1; base += 64) {
            const int myidx = (base + lane < r1) ? csrc[base + lane] : 0;
            const int cnt = min(64, r1 - base);
            int t = 0;
            for (; t + UNR <= cnt; t += UNR) {
                const float* p[UNR];
#pragma unroll
                for (int u = 0; u < UNR; u++)
                    p[u] = feat + (size_t)__shfl(myidx, t + u) * fpitch;
                float v[UNR];
#pragma unroll
                for (int u = 0; u < UNR; u++)
                    if (lane < D) v[u] = p[u][lane];
                if (lane < D) {
                    float acc = 0.0f;
#pragma unroll
                    for (int u = 0; u < UNR; u++) acc += v[u];
                    s += acc;
                }
            }
            for (; t < cnt; t++) {
                const float* fp2 = feat + (size_t)__shfl(myidx, t) * fpitch;
                if (lane < D) s += fp2[lane];
            }
        }
        if (lane < D) agg[(size_t)wid * opitch + lane] = s;
    }
}

// ---------------------------------------------------------------------------
// FUSED layer-1 kernel: h1 = relu( relu((x + agg)@W1a + b1a) @ W1b + b1b )
// Phase-1 depth-2 register prefetch (r18's variant; slightly faster).
// ---------------------------------------------------------------------------
__launch_bounds__(256)
__global__ void gemm_fused_l1(const float* __restrict__ X,
                              const float* __restrict__ A2,
                              const ushort* __restrict__ WF1,
                              const float* __restrict__ B1,
                              const ushort* __restrict__ WF2,
                              const float* __restrict__ B2,
                              float* __restrict__ OUT,
                              float* __restrict__ gsum, float* __restrict__ gsq) {
    constexpr int K1   = 114;
    constexpr int NCH1 = 4;
    constexpr int NCH2 = 7;
    constexpr int CT   = 16;
    constexpr int CTW  = 4;
    constexpr int NN   = 198;

    __shared__ __align__(16) ushort A_lds[2][2][2][4][16][8];
    __shared__ __align__(16) ushort M_lds[2][NCH2][2][4][16][8];
    __shared__ float shSum[256];
    __shared__ float shSq [256];

    const int tid  = threadIdx.x;
    const int lane = tid & 63;
    const int wv   = tid >> 6;
    const int node0 = blockIdx.x * 32;

    for (int n = tid; n < 256; n += 256) { shSum[n] = 0.0f; shSq[n] = 0.0f; }

    const int sr  = tid >> 3;
    const int sc4 = (tid & 7) * 4;
    const int skg = sc4 >> 3;
    const int sj0 = sc4 & 7;
    const int gn  = node0 + sr;
    const size_t fstride1 = (size_t)NCH1 * CT * 512;
    const size_t fstride2 = (size_t)NCH2 * CT * 512;

    float xvA[4], a2vA[4], xvB[4], a2vB[4];

    auto loadA_A = [&](int c) {
        const int k0 = c * 32 + sc4;
#pragma unroll
        for (int j = 0; j < 4; j++) {
            int gk = k0 + j;
            bool ok = (gn < NODES && gk < K1);
            xvA[j]  = ok ? X[(size_t)gn * K1 + gk] : 0.0f;
            a2vA[j] = ok ? A2[(size_t)gn * P + gk] : 0.0f;
        }
    };
    auto loadA_B = [&](int c) {
        const int k0 = c * 32 + sc4;
#pragma unroll
        for (int j = 0; j < 4; j++) {
            int gk = k0 + j;
            bool ok = (gn < NODES && gk < K1);
            xvB[j]  = ok ? X[(size_t)gn * K1 + gk] : 0.0f;
            a2vB[j] = ok ? A2[(size_t)gn * P + gk] : 0.0f;
        }
    };
    auto cvtStore = [&](int buf, int c, const float* xv, const float* a2v) {
        const int k0 = c * 32 + sc4;
        short4v hv, lv;
#pragma unroll
        for (int j = 0; j < 4; j++) {
            int gk = k0 + j;
            float t = 0.0f;
            if (gn < NODES && gk < K1) t = xv[j] + a2v[j];
            ushort h = f2bf(t);
            float hf = __uint_as_float(((uint)h) << 16);
            ushort l = f2bf(t - hf);
            hv[j] = (short)h; lv[j] = (short)l;
        }
        *(short4v*)&A_lds[buf][0][sr >> 4][skg][sr & 15][sj0] = hv;
        *(short4v*)&A_lds[buf][1][sr >> 4][skg][sr & 15][sj0] = lv;
    };

    f32x4 acc1[2][CTW] = {};
    loadA_A(0);
    loadA_B(1);
    cvtStore(0, 0, xvA, a2vA);
    __syncthreads();

    const int kg = lane >> 4, rw = lane & 15;
#pragma unroll
    for (int c = 0; c < NCH1; c++) {
        const int buf = c & 1;
        if (c + 2 < NCH1) {
            if ((c & 1) == 0) loadA_A(c + 2);
            else              loadA_B(c + 2);
        }

        short8v ah[2], al[2];
#pragma unroll
        for (int rt = 0; rt < 2; rt++) {
            ah[rt] = *(const short8v*)&A_lds[buf][0][rt][kg][rw][0];
            al[rt] = *(const short8v*)&A_lds[buf][1][rt][kg][rw][0];
        }
        const size_t fb0 = ((size_t)(c * CT + wv * CTW)) * 512 + (size_t)lane * 8;
        short8v wh = *(const short8v*)(WF1 + fb0);
        short8v wl = *(const short8v*)(WF1 + fstride1 + fb0);
#pragma unroll
        for (int t = 0; t < CTW; t++) {
            short8v nwh, nwl;
            if (t + 1 < CTW) {
                const size_t fb = fb0 + (size_t)(t + 1) * 512;
                nwh = *(const short8v*)(WF1 + fb);
                nwl = *(const short8v*)(WF1 + fstride1 + fb);
            }
            __builtin_amdgcn_s_setprio(1);
#pragma unroll
            for (int rt = 0; rt < 2; rt++) {
                acc1[rt][t] = __builtin_amdgcn_mfma_f32_16x16x32_bf16(ah[rt], wh, acc1[rt][t], 0, 0, 0);
                acc1[rt][t] = __builtin_amdgcn_mfma_f32_16x16x32_bf16(al[rt], wh, acc1[rt][t], 0, 0, 0);
                acc1[rt][t] = __builtin_amdgcn_mfma_f32_16x16x32_bf16(ah[rt], wl, acc1[rt][t], 0, 0, 0);
            }
            __builtin_amdgcn_s_setprio(0);
            if (t + 1 < CTW) { wh = nwh; wl = nwl; }
        }
        if (c + 1 < NCH1) {
            if (((c + 1) & 1) == 0) cvtStore((c + 1) & 1, c + 1, xvA, a2vA);
            else                    cvtStore((c + 1) & 1, c + 1, xvB, a2vB);
        }
        __syncthreads();
    }

    const int mg = lane >> 4, colb = lane & 15;
#pragma unroll
    for (int t = 0; t < CTW; t++) {
        const int ct = wv * CTW + t;
        if (ct >= 14) continue;
        const int n = ct * 16 + colb;
        const float bn = (n < NN) ? B1[n] : 0.0f;
        const int c2 = n >> 5, kg2 = (n >> 3) & 3, j2 = n & 7;
#pragma unroll
        for (int rt = 0; rt < 2; rt++) {
#pragma unroll
            for (int j = 0; j < 4; j++) {
                float vv = fmaxf(acc1[rt][t][j] + bn, 0.0f);
                if (n >= NN) vv = 0.0f;
                ushort h = f2bf(vv);
                float hf = __uint_as_float(((uint)h) << 16);
                ushort l = f2bf(vv - hf);
                int row = mg * 4 + j;
                M_lds[0][c2][rt][kg2][row][j2] = h;
                M_lds[1][c2][rt][kg2][row][j2] = l;
            }
        }
    }
    __syncthreads();

    f32x4 acc2[2][CTW] = {};
#pragma unroll
    for (int c = 0; c < NCH2; c++) {
        short8v ah[2], al[2];
#pragma unroll
        for (int rt = 0; rt < 2; rt++) {
            ah[rt] = *(const short8v*)&M_lds[0][c][rt][kg][rw][0];
            al[rt] = *(const short8v*)&M_lds[1][c][rt][kg][rw][0];
        }
        const size_t fb0 = ((size_t)(c * CT + wv * CTW)) * 512 + (size_t)lane * 8;
        short8v wh = *(const short8v*)(WF2 + fb0);
        short8v wl = *(const short8v*)(WF2 + fstride2 + fb0);
#pragma unroll
        for (int t = 0; t < CTW; t++) {
            short8v nwh, nwl;
            if (t + 1 < CTW) {
                const size_t fb = fb0 + (size_t)(t + 1) * 512;
                nwh = *(const short8v*)(WF2 + fb);
                nwl = *(const short8v*)(WF2 + fstride2 + fb);
            }
            __builtin_amdgcn_s_setprio(1);
#pragma unroll
            for (int rt = 0; rt < 2; rt++) {
                acc2[rt][t] = __builtin_amdgcn_mfma_f32_16x16x32_bf16(ah[rt], wh, acc2[rt][t], 0, 0, 0);
                acc2[rt][t] = __builtin_amdgcn_mfma_f32_16x16x32_bf16(al[rt], wh, acc2[rt][t], 0, 0, 0);
                acc2[rt][t] = __builtin_amdgcn_mfma_f32_16x16x32_bf16(ah[rt], wl, acc2[rt][t], 0, 0, 0);
            }
            __builtin_amdgcn_s_setprio(0);
            if (t + 1 < CTW) { wh = nwh; wl = nwl; }
        }
    }

#pragma unroll
    for (int t = 0; t < CTW; t++) {
        const int ct = wv * CTW + t;
        const int n = ct * 16 + colb;
        const float bn = (n < NN) ? B2[n] : 0.0f;
        float psum = 0.0f, psq = 0.0f;
#pragma unroll
        for (int rt = 0; rt < 2; rt++) {
#pragma unroll
            for (int j = 0; j < 4; j++) {
                int m = node0 + rt * 16 + mg * 4 + j;
                float vv = fmaxf(acc2[rt][t][j] + bn, 0.0f);
                if (m < NODES && n < NN) {
                    OUT[(size_t)m * P + n] = vv;
                    psum += vv; psq += vv * vv;
                }
            }
        }
        if (n < NN) {
            atomicAdd(&shSum[n], psum);
            atomicAdd(&shSq[n], psq);
        }
    }
    __syncthreads();
    for (int n = tid; n < NN; n += 256) {
        atomicAdd(&gsum[n], shSum[n]);
        atomicAdd(&gsq[n], shSq[n]);
    }
}

// ---------------------------------------------------------------------------
// MFMA GEMM (layers 2/3), bf16 hi/lo, KT=32, depth-2 prefetch (r17 form).
// BNX: BN coeffs derived in-kernel into LDS. WRITE=false skips global store.
// POOL: LDS per-graph reduction (batch sorted -> block spans ~1-2 graphs;
// up to 8 in LDS, else per-row fallback), then 1 global atomic/(graph,col).
// ---------------------------------------------------------------------------
template<int K, int N, bool ADD2, bool STATS, bool BNX, bool PRE, bool ACT,
         bool WRITE, bool POOL>
__launch_bounds__(256)
__global__ void gemm_mfma(const float* __restrict__ X, int xpitch,
                          const float* __restrict__ A2, int apitch,
                          const ushort* __restrict__ WF,
                          const float* __restrict__ B,
                          const float* __restrict__ PREB,
                          const float* __restrict__ bnsum, const float* __restrict__ bnsq,
                          const float* __restrict__ gamma, const float* __restrict__ beta,
                          float* __restrict__ OUT, int opitch,
                          float* __restrict__ gsum, float* __restrict__ gsq,
                          const int* __restrict__ batch, float* __restrict__ gpool) {
    constexpr int KP  = ((K + 31) / 32) * 32;
    constexpr int NCH = KP / 32;
    constexpr int NP  = ((N + 63) / 64) * 64;
    constexpr int CT  = NP / 16;
    constexpr int CTW = CT / 4;
    static_assert(CT % 4 == 0, "col tiles must split across 4 waves");

    __shared__ __align__(16) ushort A_lds[2][2][2][4][16][8];
    __shared__ float shSum[STATS ? NP : 4];
    __shared__ float shSq [STATS ? NP : 4];
    __shared__ float shSc [BNX ? 256 : 4];
    __shared__ float shSh [BNX ? 256 : 4];
    __shared__ float shPool[POOL ? 256 : 4];   // 8 graphs x 32 cols

    const int tid  = threadIdx.x;
    const int lane = tid & 63;
    const int wv   = tid >> 6;
    const int node0 = blockIdx.x * 32;

    int gfirst = 0, ng = 0;
    if (POOL) {
        gfirst = batch[min(node0, NODES - 1)];
        int glast = batch[min(node0 + 31, NODES - 1)];
        ng = glast - gfirst + 1;
        if (tid < 256) shPool[tid] = 0.0f;
    }
    if (STATS) {
        for (int n = tid; n < NP; n += 256) { shSum[n] = 0.0f; shSq[n] = 0.0f; }
    }
    if (BNX) {
        if (tid < K) {
            float mean = bnsum[tid] * (1.0f / NODES);
            float var  = bnsq[tid] * (1.0f / NODES) - mean * mean;
            var = var < 0.0f ? 0.0f : var;
            float sc = gamma[tid] * rsqrtf(var + 1e-5f);
            shSc[tid] = sc;
            shSh[tid] = beta[tid] - mean * sc;
        }
        __syncthreads();
    }

    f32x4 acc[2][CTW] = {};

    const int sr  = tid >> 3;
    const int sc4 = (tid & 7) * 4;
    const int skg = sc4 >> 3;
    const int sj0 = sc4 & 7;
    const int gn  = node0 + sr;
    const size_t fstride = (size_t)NCH * CT * 512;

    float xvA[4], xvB[4];
    float a2vA[ADD2 ? 4 : 1], a2vB[ADD2 ? 4 : 1];

    auto loadA_A = [&](int c) {
        const int k0 = c * 32 + sc4;
#pragma unroll
        for (int j = 0; j < 4; j++) {
            int gk = k0 + j;
            bool ok = (gn < NODES && gk < K);
            xvA[j] = ok ? X[(size_t)gn * xpitch + gk] : 0.0f;
            if (ADD2) a2vA[j] = ok ? A2[(size_t)gn * apitch + gk] : 0.0f;
        }
    };
    auto loadA_B = [&](int c) {
        const int k0 = c * 32 + sc4;
#pragma unroll
        for (int j = 0; j < 4; j++) {
            int gk = k0 + j;
            bool ok = (gn < NODES && gk < K);
            xvB[j] = ok ? X[(size_t)gn * xpitch + gk] : 0.0f;
            if (ADD2) a2vB[j] = ok ? A2[(size_t)gn * apitch + gk] : 0.0f;
        }
    };
    auto cvtCore = [&](int buf, int c, const float* xv, const float* a2v) {
        const int k0 = c * 32 + sc4;
        short4v hv, lv;
#pragma unroll
        for (int j = 0; j < 4; j++) {
            int gk = k0 + j;
            float t = 0.0f;
            if (gn < NODES && gk < K) {
                t = xv[j];
                if (BNX) t = fmaf(t, shSc[gk], shSh[gk]);
                if (ADD2) t += a2v[j];
                if (PRE)  t = fmaxf(t + PREB[gk], 0.0f);
            }
            ushort h = f2bf(t);
            float hf = __uint_as_float(((uint)h) << 16);
            ushort l = f2bf(t - hf);
            hv[j] = (short)h; lv[j] = (short)l;
        }
        *(short4v*)&A_lds[buf][0][sr >> 4][skg][sr & 15][sj0] = hv;
        *(short4v*)&A_lds[buf][1][sr >> 4][skg][sr & 15][sj0] = lv;
    };

    loadA_A(0);
    if (NCH > 1) loadA_B(1);
    cvtCore(0, 0, xvA, ADD2 ? a2vA : xvA);
    __syncthreads();

    const int kg = lane >> 4, rw = lane & 15;
#pragma unroll
    for (int c = 0; c < NCH; c++) {
        const int buf = c & 1;
        if (c + 2 < NCH) {
            if ((c & 1) == 0) loadA_A(c + 2);
            else              loadA_B(c + 2);
        }

        short8v ah[2], al[2];
#pragma unroll
        for (int rt = 0; rt < 2; rt++) {
            ah[rt] = *(const short8v*)&A_lds[buf][0][rt][kg][rw][0];
            al[rt] = *(const short8v*)&A_lds[buf][1][rt][kg][rw][0];
        }

        const size_t fb0 = ((size_t)(c * CT + wv * CTW)) * 512 + (size_t)lane * 8;
        short8v wh = *(const short8v*)(WF + fb0);
        short8v wl = *(const short8v*)(WF + fstride + fb0);
#pragma unroll
        for (int t = 0; t < CTW; t++) {
            short8v nwh, nwl;
            if (t + 1 < CTW) {
                const size_t fb = fb0 + (size_t)(t + 1) * 512;
                nwh = *(const short8v*)(WF + fb);
                nwl = *(const short8v*)(WF + fstride + fb);
            }
            __builtin_amdgcn_s_setprio(1);
#pragma unroll
            for (int rt = 0; rt < 2; rt++) {
                acc[rt][t] = __builtin_amdgcn_mfma_f32_16x16x32_bf16(ah[rt], wh, acc[rt][t], 0, 0, 0);
                acc[rt][t] = __builtin_amdgcn_mfma_f32_16x16x32_bf16(al[rt], wh, acc[rt][t], 0, 0, 0);
                acc[rt][t] = __builtin_amdgcn_mfma_f32_16x16x32_bf16(ah[rt], wl, acc[rt][t], 0, 0, 0);
            }
            __builtin_amdgcn_s_setprio(0);
            if (t + 1 < CTW) { wh = nwh; wl = nwl; }
        }

        if (c + 1 < NCH) {
            if (((c + 1) & 1) == 0) cvtCore((c + 1) & 1, c + 1, xvA, ADD2 ? a2vA : xvA);
            else                    cvtCore((c + 1) & 1, c + 1, xvB, ADD2 ? a2vB : xvB);
        }
        __syncthreads();
    }

    const int mg = lane >> 4, colb = lane & 15;
#pragma unroll
    for (int t = 0; t < CTW; t++) {
        const int ct = wv * CTW + t;
        const int n = ct * 16 + colb;
        const float bn = (ACT && n < N) ? B[n] : 0.0f;
        float psum = 0.0f, psq = 0.0f;
#pragma unroll
        for (int rt = 0; rt < 2; rt++) {
#pragma unroll
            for (int j = 0; j < 4; j++) {
                int m = node0 + rt * 16 + mg * 4 + j;
                float vv = ACT ? fmaxf(acc[rt][t][j] + bn, 0.0f) : acc[rt][t][j];
                if (m < NODES && n < N) {
                    if (WRITE) OUT[(size_t)m * opitch + n] = vv;
                    if (STATS) { psum += vv; psq += vv * vv; }
                    if (POOL) {
                        int g = batch[m];
                        if (ng <= 8) atomicAdd(&shPool[(g - gfirst) * 32 + n], vv);
                        else         atomicAdd(&gpool[g * 32 + n], vv);
                    }
                }
            }
        }
        if (STATS && n < N) {
            atomicAdd(&shSum[n], psum);
            atomicAdd(&shSq[n], psq);
        }
    }
    if (STATS || POOL) __syncthreads();
    if (STATS) {
        for (int n = tid; n < N; n += 256) {
            atomicAdd(&gsum[n], shSum[n]);
            atomicAdd(&gsq[n], shSq[n]);
        }
    }
    if (POOL && ng <= 8 && tid < ng * 32) {
        float v = shPool[tid];
        if (v != 0.0f) atomicAdd(&gpool[(gfirst + (tid >> 5)) * 32 + (tid & 31)], v);
    }
}

// ---------------------------------------------------------------------------
// Head MLP; BN3 coefficients derived inline, applied via linearity.
// ---------------------------------------------------------------------------
__global__ void head_kernel(const float* __restrict__ graw, const int* __restrict__ cnt,
                            const float* __restrict__ bnsum, const float* __restrict__ bnsq,
                            const float* __restrict__ gamma, const float* __restrict__ beta,
                            const float* __restrict__ fw1, const float* __restrict__ fb1,
                            const float* __restrict__ fw2, const float* __restrict__ fb2,
                            const float* __restrict__ ow, const float* __restrict__ ob,
                            float* __restrict__ out) {
    int gi = blockIdx.x * blockDim.x + threadIdx.x;
    if (gi >= GRAPHS) return;
    float cf = (float)cnt[gi];
    float v[32];
#pragma unroll
    for (int k = 0; k < 32; k++) {
        float mean = bnsum[k] * (1.0f / NODES);
        float var  = bnsq[k] * (1.0f / NODES) - mean * mean;
        var = var < 0.0f ? 0.0f : var;
        float sc = gamma[k] * rsqrtf(var + 1e-5f);
        float sh = beta[k] - mean * sc;
        v[k] = fmaf(graw[gi * 32 + k], sc, cf * sh);
    }
    float a1[16];
#pragma unroll
    for (int o = 0; o < 16; o++) {
        float s = fb1[o];
#pragma unroll
        for (int k = 0; k < 32; k++) s = fmaf(v[k], fw1[k * 16 + o], s);
        a1[o] = s > 0.0f ? s : 0.0f;
    }
    float a2[8];
#pragma unroll
    for (int o = 0; o < 8; o++) {
        float s = fb2[o];
#pragma unroll
        for (int k = 0; k < 16; k++) s = fmaf(a1[k], fw2[k * 8 + o], s);
        a2[o] = s > 0.0f ? s : 0.0f;
    }
#pragma unroll
    for (int o = 0; o < 2; o++) {
        float s = ob[o];
#pragma unroll
        for (int k = 0; k < 8; k++) s = fmaf(a2[k], ow[k * 2 + o], s);
        out[gi * 2 + o] = s;
    }
}

// ---------------------------------------------------------------------------
extern "C" void kernel_launch(void* const* d_in, const int* in_sizes, int n_in,
                              void* d_out, int out_size, void* d_ws, size_t ws_size,
                              hipStream_t stream) {
    const float* x     = (const float*)d_in[0];
    const int*   ei    = (const int*)d_in[1];
    const int*   batch = (const int*)d_in[2];
    const float *w1a = (const float*)d_in[3],  *b1a = (const float*)d_in[4];
    const float *w1b = (const float*)d_in[5],  *b1b = (const float*)d_in[6];
    const float *g1  = (const float*)d_in[7],  *be1 = (const float*)d_in[8];
    const float *w2a = (const float*)d_in[9],  *b2a = (const float*)d_in[10];
    const float *w2b = (const float*)d_in[11], *b2b = (const float*)d_in[12];
    const float *g2  = (const float*)d_in[13], *be2 = (const float*)d_in[14];
    const float *w3a = (const float*)d_in[15], *b3a = (const float*)d_in[16];
    const float *w3b = (const float*)d_in[17], *b3b = (const float*)d_in[18];
    const float *g3  = (const float*)d_in[19], *be3 = (const float*)d_in[20];
    const float *fw1 = (const float*)d_in[21], *fb1 = (const float*)d_in[22];
    const float *fw2 = (const float*)d_in[23], *fb2 = (const float*)d_in[24];
    const float *ow  = (const float*)d_in[25], *ob  = (const float*)d_in[26];
    const int* src = ei;
    const int* dst = ei + EDGES;

    float* ws  = (float*)d_ws;
    float* b0  = ws;                                   // 50000 x 200
    float* b1  = ws + (size_t)NODES * P;               // 50000 x 200
    float* Y2  = b1;                                   // 50000 x 64 (in b1)
    float* AG2 = b1 + (size_t)NODES * 64;              // 50000 x 64 (in b1)
    float* Y3  = b1;                                   // 50000 x 32 (in b1)
    float* AG3 = b1 + (size_t)NODES * 32;              // 50000 x 32 (in b1)

    // ---- contiguous ZERO region (one memset per launch) ----
    int*   deg  = (int*)(ws + (size_t)2 * NODES * P);  // 50000
    int*   cnt  = deg + NODES;                         // 1024
    float* SUM1 = (float*)(cnt + GRAPHS);              // 6 x 256 stat buffers
    float* SQ1  = SUM1 + 256;
    float* SUM2 = SQ1 + 256;
    float* SQ2  = SUM2 + 256;
    float* SUM3 = SQ2 + 256;
    float* SQ3  = SUM3 + 256;
    float* G    = SQ3 + 256;                           // 1024 x 32 raw pool
    const size_t ZERO_ELEMS = (size_t)NODES + GRAPHS + 6 * 256 + (size_t)GRAPHS * 32;
    // ---- end zero region ----

    int* rowstart = (int*)(G + (size_t)GRAPHS * 32);   // 50001
    int* cursor   = rowstart + NODES + 1;              // 50000
    int* part     = cursor + NODES;                    // 256
    int* csrc     = part + 256;                        // 800000
    uintptr_t wfp = ((uintptr_t)(csrc + EDGES) + 15) & ~(uintptr_t)15;
    ushort* WF1 = (ushort*)wfp;                        // 65536
    ushort* WF2 = WF1 + 65536;                         // 114688
    ushort* WF3 = WF2 + 114688;                        // 28672
    ushort* WF4 = WF3 + 28672;                         // 8192
    ushort* WF5 = WF4 + 8192;                          // 8192
    ushort* WF6 = WF5 + 8192;                          // 4096
    float* out = (float*)d_out;

    const int GBR  = (NODES + 31) / 32;       // 1563 gemm blocks (32-row)
    const int AB   = (NODES * 64 + 255) / 256;            // 1 node / wave
    const int AB2  = (((NODES + 1) / 2) * 64 + 255) / 256; // 2 nodes / wave
    const int EB   = (EDGES + 255) / 256;

    // ---- weight conversion (1 dispatch) + zeroing (1 memset) ----
    pad_all<<<(229376 + 255) / 256, 256, 0, stream>>>(w1a, w1b, w2a, w2b, w3a, w3b,
                                                      WF1, WF2, WF3, WF4, WF5, WF6);
    hipMemsetAsync(deg, 0, ZERO_ELEMS * sizeof(int), stream);

    // ---- CSR build (+ per-graph counts) ----
    hist_kernel<<<EB, 256, 0, stream>>>(dst, deg, batch, cnt);
    scan_part<<<SCAN_NB, SCAN_BLK, 0, stream>>>(deg, part);
    scan_scan<<<1, SCAN_BLK, 0, stream>>>(part);
    scan_expand<<<SCAN_NB, SCAN_BLK, 0, stream>>>(deg, part, rowstart, cursor);
    scatter_kernel<<<EB, 256, 0, stream>>>(src, dst, cursor, csrc);

    // ---- layer 1 (114 -> 198 -> 198): agg-first + fused double GEMM ----
    csr_agg<114><<<AB, 256, 0, stream>>>(x, 114, rowstart, csrc, b0, P);
    gemm_fused_l1<<<GBR, 256, 0, stream>>>(x, b0, WF1, b1a, WF2, b1b, b0, SUM1, SQ1);

    // ---- layer 2 (198 -> 64 -> 64): aggregate-after at D=64; BN1 in-kernel ----
    gemm_mfma<198, 64, false, false, true, false, false, true, false><<<GBR, 256, 0, stream>>>(
        b0, P, nullptr, 0, WF3, nullptr, nullptr, SUM1, SQ1, g1, be1,
        Y2, 64, nullptr, nullptr, nullptr, nullptr);
    csr_agg<64><<<AB, 256, 0, stream>>>(Y2, 64, rowstart, csrc, AG2, 64);
    gemm_mfma<64, 64, true, true, false, true, true, true, false><<<GBR, 256, 0, stream>>>(
        Y2, 64, AG2, 64, WF4, b2b, b2a, nullptr, nullptr, nullptr, nullptr,
        b0, 64, SUM2, SQ2, nullptr, nullptr);

    // ---- layer 3 (64 -> 32 -> 32): aggregate-after at D=32; BN2 in-kernel ----
    gemm_mfma<64, 32, false, false, true, false, false, true, false><<<GBR, 256, 0, stream>>>(
        b0, 64, nullptr, 0, WF5, nullptr, nullptr, SUM2, SQ2, g2, be2,
        Y3, 32, nullptr, nullptr, nullptr, nullptr);
    csr_agg<32><<<AB2, 256, 0, stream>>>(Y3, 32, rowstart, csrc, AG3, 32);
    gemm_mfma<32, 32, true, true, false, true, true, false, true><<<GBR, 256, 0, stream>>>(
        Y3, 32, AG3, 32, WF6, b3b, b3a, nullptr, nullptr, nullptr, nullptr,
        nullptr, 32, SUM3, SQ3, batch, G);

    // ---- head (BN3 derived inline, applied via linearity) ----
    head_kernel<<<(GRAPHS + 255) / 256, 256, 0, stream>>>(
        G, cnt, SUM3, SQ3, g3, be3, fw1, fb1, fw2, fb2, ow, ob, out);
}